// Round 2
// baseline (28.146 us; speedup 1.0000x reference)
//
#include <hip/hip_runtime.h>

// QSP response, per element n:  a = w_real[n,0,0], s = w_imag[n,0,1].
// State = column 0 of M (2 complex numbers). 63 steps of
//   m <- diag(e^{-i th/2}, e^{+i th/2}) * (a*I + i*s*X) * m
// out = Re(m0 + m1) / sqrt(2).
// Phase table (cos,sin of phi_k/2) is wave-uniform -> LDS as float4 pairs
// (one ds_read_b128 covers 2 phases). 2 elements per thread for ILP.

static constexpr float kInvSqrt2 = 0.70710678118654752440f;

// One QSP step on one chain (16 VALU ops).
#define QSTEP(c, sp, a, s, m0r, m0i, m1r, m1i)      \
    do {                                            \
        float t0r = fmaf(a, m0r, -(s) * m1i);       \
        float t0i = fmaf(a, m0i,  (s) * m1r);       \
        float t1r = fmaf(a, m1r, -(s) * m0i);       \
        float t1i = fmaf(a, m1i,  (s) * m0r);       \
        m0r = fmaf(c, t0r,  (sp) * t0i);            \
        m0i = fmaf(c, t0i, -(sp) * t0r);            \
        m1r = fmaf(c, t1r, -(sp) * t1i);            \
        m1i = fmaf(c, t1i,  (sp) * t1r);            \
    } while (0)

__global__ __launch_bounds__(256) void qsp_kernel(
    const float* __restrict__ phi,
    const float4* __restrict__ w_real,   // [N] float4, .x = a
    const float4* __restrict__ w_imag,   // [N] float4, .y = s
    float* __restrict__ out,
    int n)
{
    __shared__ float4 tab[32];           // tab[kk] = (c[2kk], s[2kk], c[2kk+1], s[2kk+1])
    if (threadIdx.x < 32) {
        const int k0 = 2 * (int)threadIdx.x;
        float s0, c0, s1, c1;
        sincosf(0.5f * phi[k0],     &s0, &c0);
        sincosf(0.5f * phi[k0 + 1], &s1, &c1);
        tab[threadIdx.x] = make_float4(c0, s0, c1, s1);
    }
    __syncthreads();

    const int i0 = blockIdx.x * 512 + (int)threadIdx.x;  // chain A
    const int i1 = i0 + 256;                             // chain B
    if (i0 >= n) return;

    const float aA = w_real[i0].x;
    const float sA = w_imag[i0].y;
    const bool haveB = (i1 < n);
    const float aB = haveB ? w_real[i1].x : 0.0f;
    const float sB = haveB ? w_imag[i1].y : 0.0f;

    const float4 t0 = tab[0];
    // init: m = RZ(phi0) * H column 0
    float A0r = kInvSqrt2 * t0.x, A0i = -kInvSqrt2 * t0.y;
    float A1r = kInvSqrt2 * t0.x, A1i =  kInvSqrt2 * t0.y;
    float B0r = A0r, B0i = A0i, B1r = A1r, B1i = A1i;

    // phase 1 from t0.zw
    QSTEP(t0.z, t0.w, aA, sA, A0r, A0i, A1r, A1i);
    QSTEP(t0.z, t0.w, aB, sB, B0r, B0i, B1r, B1i);

#pragma unroll
    for (int kk = 1; kk < 32; ++kk) {    // phases 2..63, two per float4
        const float4 t = tab[kk];
        QSTEP(t.x, t.y, aA, sA, A0r, A0i, A1r, A1i);
        QSTEP(t.x, t.y, aB, sB, B0r, B0i, B1r, B1i);
        QSTEP(t.z, t.w, aA, sA, A0r, A0i, A1r, A1i);
        QSTEP(t.z, t.w, aB, sB, B0r, B0i, B1r, B1i);
    }

    out[i0] = (A0r + A1r) * kInvSqrt2;
    if (haveB) out[i1] = (B0r + B1r) * kInvSqrt2;
}

extern "C" void kernel_launch(void* const* d_in, const int* in_sizes, int n_in,
                              void* d_out, int out_size, void* d_ws, size_t ws_size,
                              hipStream_t stream) {
    const float*  phi    = (const float*)d_in[0];
    const float4* w_real = (const float4*)d_in[1];
    const float4* w_imag = (const float4*)d_in[2];
    float* out = (float*)d_out;

    const int n = in_sizes[1] / 4;                 // N elements
    const int block = 256;
    const int grid = (n + 2 * block - 1) / (2 * block);  // 2 elems/thread
    qsp_kernel<<<grid, block, 0, stream>>>(phi, w_real, w_imag, out, n);
}

// Round 3
// 24.530 us; speedup vs baseline: 1.1474x; 1.1474x over previous
//
#include <hip/hip_runtime.h>

// QSP response via packed-FP32 (v_pk_*_f32): two elements per thread, one in
// each half of a 64-bit VGPR pair. State = column 0 of M as 4 real pairs
// (M0R,M0I,M1R,M1I), 63 steps of m <- RZ(th)*W*m, out = Re(m0+m1)/sqrt2.
// All ops are component-independent -> plain v_pk_mul/v_pk_fma, no op_sel.

typedef float f32x2 __attribute__((ext_vector_type(2)));
typedef float f32x4 __attribute__((ext_vector_type(4)));

static constexpr float kInvSqrt2 = 0.70710678118654752440f;

__device__ __forceinline__ f32x2 pk_mul(f32x2 a, f32x2 b) {
    f32x2 d;
    asm("v_pk_mul_f32 %0, %1, %2" : "=v"(d) : "v"(a), "v"(b));
    return d;
}
__device__ __forceinline__ f32x2 pk_fma(f32x2 a, f32x2 b, f32x2 c) {
    f32x2 d;
    asm("v_pk_fma_f32 %0, %1, %2, %3" : "=v"(d) : "v"(a), "v"(b), "v"(c));
    return d;
}

__global__ __launch_bounds__(256) void qsp_kernel(
    const float* __restrict__ phi,
    const float4* __restrict__ w_real,   // [N] float4, .x = a
    const float4* __restrict__ w_imag,   // [N] float4, .y = s
    float* __restrict__ out,
    int n)
{
    __shared__ f32x4 tabP[64];   // (c, c, st, st)   c=cos(phi/2), st=sin(phi/2)
    __shared__ f32x2 tabN[64];   // (-st, -st)
    if (threadIdx.x < 64) {
        float st, c;
        sincosf(0.5f * phi[threadIdx.x], &st, &c);
        tabP[threadIdx.x] = (f32x4){c, c, st, st};
        tabN[threadIdx.x] = (f32x2){-st, -st};
    }
    __syncthreads();

    const int i0 = (int)blockIdx.x * 512 + (int)threadIdx.x;  // elem A
    const int i1 = i0 + 256;                                  // elem B
    if (i0 >= n) return;
    const int i1c = (i1 < n) ? i1 : i0;                       // clamp for load

    const float4 wrA = w_real[i0], wrB = w_real[i1c];
    const float4 wiA = w_imag[i0], wiB = w_imag[i1c];
    const f32x2 aP  = (f32x2){wrA.x, wrB.x};
    const f32x2 sP  = (f32x2){wiA.y, wiB.y};
    const f32x2 nsP = (f32x2){-wiA.y, -wiB.y};

    // init: m = RZ(phi0) * H column 0 (element-independent)
    const f32x4 t0 = tabP[0];
    const float m0r0 = kInvSqrt2 * t0.x;
    const float m0i0 = -kInvSqrt2 * t0.z;
    f32x2 M0R = (f32x2){m0r0, m0r0};
    f32x2 M0I = (f32x2){m0i0, m0i0};
    f32x2 M1R = (f32x2){m0r0, m0r0};
    f32x2 M1I = (f32x2){-m0i0, -m0i0};

#pragma unroll 3
    for (int k = 1; k < 64; ++k) {
        const f32x4 tp = tabP[k];
        const f32x2 tn = tabN[k];
        const f32x2 C  = __builtin_shufflevector(tp, tp, 0, 1);  // (c,c)
        const f32x2 S  = __builtin_shufflevector(tp, tp, 2, 3);  // (st,st)
        // T = W * M,  W = a*I + i*s*X
        const f32x2 T0R = pk_fma(aP, M0R, pk_mul(nsP, M1I));
        const f32x2 T0I = pk_fma(aP, M0I, pk_mul(sP,  M1R));
        const f32x2 T1R = pk_fma(aP, M1R, pk_mul(nsP, M0I));
        const f32x2 T1I = pk_fma(aP, M1I, pk_mul(sP,  M0R));
        // M = diag(e^{-i th/2}, e^{+i th/2}) * T
        M0R = pk_fma(C, T0R, pk_mul(S,  T0I));
        M0I = pk_fma(C, T0I, pk_mul(tn, T0R));
        M1R = pk_fma(C, T1R, pk_mul(tn, T1I));
        M1I = pk_fma(C, T1I, pk_mul(S,  T1R));
    }

    out[i0] = (M0R.x + M1R.x) * kInvSqrt2;
    if (i1 < n) out[i1] = (M0R.y + M1R.y) * kInvSqrt2;
}

extern "C" void kernel_launch(void* const* d_in, const int* in_sizes, int n_in,
                              void* d_out, int out_size, void* d_ws, size_t ws_size,
                              hipStream_t stream) {
    const float*  phi    = (const float*)d_in[0];
    const float4* w_real = (const float4*)d_in[1];
    const float4* w_imag = (const float4*)d_in[2];
    float* out = (float*)d_out;

    const int n = in_sizes[1] / 4;                       // N elements
    const int block = 256;
    const int grid = (n + 2 * block - 1) / (2 * block);  // 2 elems/thread
    qsp_kernel<<<grid, block, 0, stream>>>(phi, w_real, w_imag, out, n);
}

// Round 4
// 15.299 us; speedup vs baseline: 1.8397x; 1.6034x over previous
//
#include <hip/hip_runtime.h>

// QSP response decomposed: Re(u00)(a) = F(a) + s*G(a), s = sqrt(1-a^2),
// where F (odd, deg<=63) and G (even, deg<=62) depend only on phi.
// With x = 2a^2-1:  F(a) = a*R(x), G(a) = Gh(x), R/Gh of degree <= 31.
// Kernel 1 (1 block): sample u at 64 Chebyshev nodes (+-cos(pi(j+.5)/64))
// via the verified direct 63-step iteration, split even/odd parts, 32-pt
// DCT-II -> Chebyshev coeffs r[32], g[32] in d_ws.
// Kernel 2 (N elems): two fused 31-step Clenshaws; out = a*R(x) + s*Gh(x).

static constexpr float kInvSqrt2 = 0.70710678118654752440f;
static constexpr float kPiF = 3.14159265358979323846f;

#define QSTEP(c, sp, a, s, m0r, m0i, m1r, m1i)      \
    do {                                            \
        float t0r = fmaf(a, m0r, -(s) * m1i);       \
        float t0i = fmaf(a, m0i,  (s) * m1r);       \
        float t1r = fmaf(a, m1r, -(s) * m0i);       \
        float t1i = fmaf(a, m1i,  (s) * m0r);       \
        m0r = fmaf(c, t0r,  (sp) * t0i);            \
        m0i = fmaf(c, t0i, -(sp) * t0r);            \
        m1r = fmaf(c, t1r, -(sp) * t1i);            \
        m1i = fmaf(c, t1i,  (sp) * t1r);            \
    } while (0)

__global__ __launch_bounds__(64) void qsp_coeff_kernel(
    const float* __restrict__ phi,
    float* __restrict__ coef)        // coef[2k]=r_k, coef[2k+1]=g_k
{
    __shared__ float tc[64], ts[64];
    __shared__ float ubuf[64];
    __shared__ float rbuf[32], gbuf[32];

    const int l = (int)threadIdx.x;
    {
        float sv, cv;
        sincosf(0.5f * phi[l], &sv, &cv);
        tc[l] = cv; ts[l] = sv;
    }
    __syncthreads();

    // node: a = +-cos(pi*(j+.5)/64), lanes 0..31 positive, 32..63 negative
    const int j = l & 31;
    float sn, cn;
    sincosf(kPiF * ((float)j + 0.5f) / 64.0f, &sn, &cn);
    const float a = (l < 32) ? cn : -cn;
    const float s = sn;

    float m0r, m0i, m1r, m1i;
    {
        const float c0 = tc[0], s0 = ts[0];
        m0r = kInvSqrt2 * c0; m0i = -kInvSqrt2 * s0;
        m1r = kInvSqrt2 * c0; m1i =  kInvSqrt2 * s0;
    }
#pragma unroll
    for (int k = 1; k < 64; ++k) {
        QSTEP(tc[k], ts[k], a, s, m0r, m0i, m1r, m1i);
    }
    ubuf[l] = (m0r + m1r) * kInvSqrt2;   // u at this node
    __syncthreads();

    if (l < 32) {
        const float up = ubuf[l], um = ubuf[l + 32];
        rbuf[l] = (up - um) * (0.5f / cn);   // R(x_j) = F(a_j)/a_j
        gbuf[l] = (up + um) * (0.5f / sn);   // Gh(x_j) = G(a_j)
    }
    __syncthreads();

    // 32-point DCT-II: c_k = (2-d_{k0})/32 * sum_m f(x_m) cos(k*psi_m),
    // psi_m = pi*(m+.5)/32. Lane k<32 -> r_k over rbuf; k>=32 -> g over gbuf.
    const float* buf = (l < 32) ? rbuf : gbuf;
    const float stepang = kPiF * (float)j / 32.0f;
    float C, S;  sincosf(stepang, &S, &C);
    float cv, sv; sincosf(0.5f * stepang, &sv, &cv);   // angle k*psi_0
    float acc = 0.0f;
#pragma unroll
    for (int m = 0; m < 32; ++m) {
        acc = fmaf(buf[m], cv, acc);
        const float cnx = cv * C - sv * S;     // rotate by stepang
        sv = fmaf(cv, S, sv * C);
        cv = cnx;
    }
    acc *= (j == 0) ? (1.0f / 32.0f) : (2.0f / 32.0f);

    if (l < 32) coef[2 * j]     = acc;
    else        coef[2 * j + 1] = acc;
}

__global__ __launch_bounds__(256) void qsp_eval_kernel(
    const float4* __restrict__ w_real,   // [N] float4, .x = a
    const float* __restrict__ coef,
    float* __restrict__ out,
    int n)
{
    __shared__ float2 tab[32];           // (r_k, g_k)
    if (threadIdx.x < 32)
        tab[threadIdx.x] = ((const float2*)coef)[threadIdx.x];
    __syncthreads();

    const int i = blockIdx.x * blockDim.x + (int)threadIdx.x;
    if (i >= n) return;

    const float a = w_real[i].x;
    const float x = fmaf(a + a, a, -1.0f);                    // 2a^2-1
    const float s = sqrtf(fmaxf(fmaf(-a, a, 1.0f), 0.0f));    // sqrt(1-a^2)
    const float x2 = x + x;

    float bf1 = 0.f, bf2 = 0.f, bg1 = 0.f, bg2 = 0.f;
#pragma unroll
    for (int k = 31; k >= 1; --k) {
        const float2 t = tab[k];
        const float nf = fmaf(x2, bf1, t.x - bf2);
        const float ng = fmaf(x2, bg1, t.y - bg2);
        bf2 = bf1; bf1 = nf;
        bg2 = bg1; bg1 = ng;
    }
    const float2 t0 = tab[0];
    const float R = fmaf(x, bf1, t0.x - bf2);
    const float G = fmaf(x, bg1, t0.y - bg2);

    out[i] = fmaf(a, R, s * G);          // F + s*G
}

extern "C" void kernel_launch(void* const* d_in, const int* in_sizes, int n_in,
                              void* d_out, int out_size, void* d_ws, size_t ws_size,
                              hipStream_t stream) {
    const float*  phi    = (const float*)d_in[0];
    const float4* w_real = (const float4*)d_in[1];
    float* out  = (float*)d_out;
    float* coef = (float*)d_ws;          // 64 floats

    const int n = in_sizes[1] / 4;       // N elements
    qsp_coeff_kernel<<<1, 64, 0, stream>>>(phi, coef);
    const int block = 256;
    const int grid = (n + block - 1) / block;
    qsp_eval_kernel<<<grid, block, 0, stream>>>(w_real, coef, out, n);
}

// Round 5
// 12.729 us; speedup vs baseline: 2.2111x; 1.2019x over previous
//
#include <hip/hip_runtime.h>

// Fused QSP: Re(u00)(a) = a*R(x) + s*Gh(x), x = 2a^2-1, s = sqrt(1-a^2),
// R/Gh deg-31 Chebyshev polys depending only on phi.
// Every block: wave0 samples u at 64 Chebyshev nodes via the direct 63-step
// iteration, splits even/odd, 32-pt DCT-II -> 64 coeffs in LDS (other waves
// wait at barriers with their global loads already in flight). Then all
// threads pull coeffs into registers (16x ds_read_b128 broadcast) and eval
// 8 elements each with a shared T_k recurrence + two register-dot-products.

static constexpr float kInvSqrt2 = 0.70710678118654752440f;
static constexpr float kPiF = 3.14159265358979323846f;

#define QSTEP(c, sp, a, s, m0r, m0i, m1r, m1i)      \
    do {                                            \
        float t0r = fmaf(a, m0r, -(s) * m1i);       \
        float t0i = fmaf(a, m0i,  (s) * m1r);       \
        float t1r = fmaf(a, m1r, -(s) * m0i);       \
        float t1i = fmaf(a, m1i,  (s) * m0r);       \
        m0r = fmaf(c, t0r,  (sp) * t0i);            \
        m0i = fmaf(c, t0i, -(sp) * t0r);            \
        m1r = fmaf(c, t1r, -(sp) * t1i);            \
        m1i = fmaf(c, t1i,  (sp) * t1r);            \
    } while (0)

#define ELEMS 8
#define BLKSZ 256

__global__ __launch_bounds__(256) void qsp_fused(
    const float* __restrict__ phi,
    const float* __restrict__ w_real,   // [N*4] floats; a = w_real[4*i]
    float* __restrict__ out,
    int n)
{
    __shared__ float tc[64], ts[64];
    __shared__ float ubuf[64];
    __shared__ float rbuf[32], gbuf[32];
    __shared__ float4 ctab4[16];        // (r_2i, g_2i, r_2i+1, g_2i+1)

    const int t = (int)threadIdx.x;
    const int base = (int)blockIdx.x * (BLKSZ * ELEMS) + t;

    // Phase A: issue all input loads now; consumed only after coeff phases.
    float av[ELEMS];
#pragma unroll
    for (int e = 0; e < ELEMS; ++e)
        av[e] = w_real[(size_t)(base + e * BLKSZ) * 4];

    // Phase B: phase table (wave0 only)
    if (t < 64) {
        float sv, cv;
        sincosf(0.5f * phi[t], &sv, &cv);
        tc[t] = cv; ts[t] = sv;
    }
    __syncthreads();

    // Phase C: direct 63-step iteration at 64 Chebyshev nodes (wave0 only)
    if (t < 64) {
        const int j = t & 31;
        float sn, cn;
        sincosf(kPiF * ((float)j + 0.5f) / 64.0f, &sn, &cn);
        const float a = (t < 32) ? cn : -cn;
        const float s = sn;
        const float c0 = tc[0], s0 = ts[0];
        float m0r = kInvSqrt2 * c0, m0i = -kInvSqrt2 * s0;
        float m1r = kInvSqrt2 * c0, m1i =  kInvSqrt2 * s0;
#pragma unroll
        for (int k = 1; k < 64; ++k)
            QSTEP(tc[k], ts[k], a, s, m0r, m0i, m1r, m1i);
        ubuf[t] = (m0r + m1r) * kInvSqrt2;
    }
    __syncthreads();

    // Phase D: split into R(x_j), Gh(x_j) samples
    if (t < 32) {
        float sn, cn;
        sincosf(kPiF * ((float)t + 0.5f) / 64.0f, &sn, &cn);
        const float up = ubuf[t], um = ubuf[t + 32];
        rbuf[t] = (up - um) * (0.5f / cn);
        gbuf[t] = (up + um) * (0.5f / sn);
    }
    __syncthreads();

    // Phase E: 32-point DCT-II -> Chebyshev coeffs (wave0; lanes<32 do r, >=32 do g)
    if (t < 64) {
        const int j = t & 31;
        const float* buf = (t < 32) ? rbuf : gbuf;
        const float stepang = kPiF * (float)j / 32.0f;
        float C, S;  sincosf(stepang, &S, &C);
        float cv, sv; sincosf(0.5f * stepang, &sv, &cv);
        float acc = 0.0f;
#pragma unroll
        for (int m = 0; m < 32; ++m) {
            acc = fmaf(buf[m], cv, acc);
            const float cnx = cv * C - sv * S;
            sv = fmaf(cv, S, sv * C);
            cv = cnx;
        }
        acc *= (j == 0) ? (1.0f / 32.0f) : (2.0f / 32.0f);
        ((float*)ctab4)[(t < 32) ? (2 * j) : (2 * j + 1)] = acc;
    }
    __syncthreads();

    // Phase F: coeffs -> registers (broadcast b128 reads), eval 8 elems/thread
    float4 cf[16];
#pragma unroll
    for (int i = 0; i < 16; ++i) cf[i] = ctab4[i];

#pragma unroll
    for (int e = 0; e < ELEMS; ++e) {
        const float a  = av[e];
        const float aa = a * a;
        const float x  = fmaf(2.0f, aa, -1.0f);
        const float s  = sqrtf(fmaxf(1.0f - aa, 0.0f));
        const float x2 = x + x;
        float accR = fmaf(x, cf[0].z, cf[0].x);   // r0 + r1*T1
        float accG = fmaf(x, cf[0].w, cf[0].y);
        float tm2 = 1.0f, tm1 = x;
#pragma unroll
        for (int k = 2; k < 32; ++k) {
            const float tk = fmaf(x2, tm1, -tm2);
            const float rk = (k & 1) ? cf[k >> 1].z : cf[k >> 1].x;
            const float gk = (k & 1) ? cf[k >> 1].w : cf[k >> 1].y;
            accR = fmaf(tk, rk, accR);
            accG = fmaf(tk, gk, accG);
            tm2 = tm1; tm1 = tk;
        }
        out[base + e * BLKSZ] = fmaf(a, accR, s * accG);
    }
}

extern "C" void kernel_launch(void* const* d_in, const int* in_sizes, int n_in,
                              void* d_out, int out_size, void* d_ws, size_t ws_size,
                              hipStream_t stream) {
    const float* phi    = (const float*)d_in[0];
    const float* w_real = (const float*)d_in[1];
    float* out = (float*)d_out;

    const int n = in_sizes[1] / 4;               // N = 2^20
    const int grid = n / (BLKSZ * ELEMS);        // 512 blocks, exact
    qsp_fused<<<grid, BLKSZ, 0, stream>>>(phi, w_real, out, n);
}

// Round 6
// 12.656 us; speedup vs baseline: 2.2239x; 1.0058x over previous
//
#include <hip/hip_runtime.h>

// Fused QSP: Re(u00)(a) = a*R(x) + s*Gh(x), x = 2a^2-1, s = sqrt(1-a^2),
// R/Gh deg-31 Chebyshev polys depending only on phi.
// Per block: wave0 builds the coeff table (64-node direct iteration + 32-pt
// DCT-II) while waves 1-3 precompute x,s per element (coeff-independent).
// Then all threads pull the 64 coeffs into registers and do shared-T_k
// dot products, 4 elements/thread. 1024 blocks -> 4 blocks/CU, 4 waves/SIMD.

static constexpr float kInvSqrt2 = 0.70710678118654752440f;
static constexpr float kPiF = 3.14159265358979323846f;

#define QSTEP(c, sp, a, s, m0r, m0i, m1r, m1i)      \
    do {                                            \
        float t0r = fmaf(a, m0r, -(s) * m1i);       \
        float t0i = fmaf(a, m0i,  (s) * m1r);       \
        float t1r = fmaf(a, m1r, -(s) * m0i);       \
        float t1i = fmaf(a, m1i,  (s) * m0r);       \
        m0r = fmaf(c, t0r,  (sp) * t0i);            \
        m0i = fmaf(c, t0i, -(sp) * t0r);            \
        m1r = fmaf(c, t1r, -(sp) * t1i);            \
        m1i = fmaf(c, t1i,  (sp) * t1r);            \
    } while (0)

#define ELEMS 4
#define BLKSZ 256

__global__ __launch_bounds__(256, 4) void qsp_fused(
    const float* __restrict__ phi,
    const float* __restrict__ w_real,   // [N*4] floats; a = w_real[4*i]
    float* __restrict__ out,
    int n)
{
    __shared__ float tc[64], ts[64];
    __shared__ float ubuf[64];
    __shared__ float rbuf[32], gbuf[32];
    __shared__ float4 ctab4[16];        // (r_2i, g_2i, r_2i+1, g_2i+1)

    const int t = (int)threadIdx.x;
    const int base = (int)blockIdx.x * (BLKSZ * ELEMS) + t;

    // Issue input loads immediately.
    float av[ELEMS];
#pragma unroll
    for (int e = 0; e < ELEMS; ++e)
        av[e] = w_real[(size_t)(base + e * BLKSZ) * 4];

    // Wave0: phase table.
    if (t < 64) {
        float sv, cv;
        sincosf(0.5f * phi[t], &sv, &cv);
        tc[t] = cv; ts[t] = sv;
    }

    // All waves: coeff-independent per-element prep (hides under coeff phase).
    float xv[ELEMS], sv_[ELEMS], x2v[ELEMS];
#pragma unroll
    for (int e = 0; e < ELEMS; ++e) {
        const float a  = av[e];
        const float aa = a * a;
        xv[e]  = fmaf(2.0f, aa, -1.0f);
        sv_[e] = sqrtf(fmaxf(1.0f - aa, 0.0f));
        x2v[e] = xv[e] + xv[e];
    }
    __syncthreads();

    // Wave0: direct 63-step iteration at 64 Chebyshev nodes.
    if (t < 64) {
        const int j = t & 31;
        float sn, cn;
        sincosf(kPiF * ((float)j + 0.5f) / 64.0f, &sn, &cn);
        const float a = (t < 32) ? cn : -cn;
        const float s = sn;
        const float c0 = tc[0], s0 = ts[0];
        float m0r = kInvSqrt2 * c0, m0i = -kInvSqrt2 * s0;
        float m1r = kInvSqrt2 * c0, m1i =  kInvSqrt2 * s0;
#pragma unroll
        for (int k = 1; k < 64; ++k)
            QSTEP(tc[k], ts[k], a, s, m0r, m0i, m1r, m1i);
        ubuf[t] = (m0r + m1r) * kInvSqrt2;
    }
    __syncthreads();

    // Wave0: even/odd split -> R(x_j), Gh(x_j) samples.
    if (t < 32) {
        float sn, cn;
        sincosf(kPiF * ((float)t + 0.5f) / 64.0f, &sn, &cn);
        const float up = ubuf[t], um = ubuf[t + 32];
        rbuf[t] = (up - um) * (0.5f / cn);
        gbuf[t] = (up + um) * (0.5f / sn);
    }
    __syncthreads();

    // Wave0: 32-point DCT-II -> Chebyshev coeffs (lanes<32 r, lanes>=32 g).
    if (t < 64) {
        const int j = t & 31;
        const float* buf = (t < 32) ? rbuf : gbuf;
        const float stepang = kPiF * (float)j / 32.0f;
        float C, S;  sincosf(stepang, &S, &C);
        float cv, sv; sincosf(0.5f * stepang, &sv, &cv);
        float acc = 0.0f;
#pragma unroll
        for (int m = 0; m < 32; ++m) {
            acc = fmaf(buf[m], cv, acc);
            const float cnx = cv * C - sv * S;
            sv = fmaf(cv, S, sv * C);
            cv = cnx;
        }
        acc *= (j == 0) ? (1.0f / 32.0f) : (2.0f / 32.0f);
        ((float*)ctab4)[(t < 32) ? (2 * j) : (2 * j + 1)] = acc;
    }
    __syncthreads();

    // All threads: coeffs -> registers (broadcast b128), shared-T_k eval.
    float4 cf[16];
#pragma unroll
    for (int i = 0; i < 16; ++i) cf[i] = ctab4[i];

#pragma unroll
    for (int e = 0; e < ELEMS; ++e) {
        const float x  = xv[e];
        const float x2 = x2v[e];
        float accR = fmaf(x, cf[0].z, cf[0].x);
        float accG = fmaf(x, cf[0].w, cf[0].y);
        float tm2 = 1.0f, tm1 = x;
#pragma unroll
        for (int k = 2; k < 32; ++k) {
            const float tk = fmaf(x2, tm1, -tm2);
            const float rk = (k & 1) ? cf[k >> 1].z : cf[k >> 1].x;
            const float gk = (k & 1) ? cf[k >> 1].w : cf[k >> 1].y;
            accR = fmaf(tk, rk, accR);
            accG = fmaf(tk, gk, accG);
            tm2 = tm1; tm1 = tk;
        }
        out[base + e * BLKSZ] = fmaf(av[e], accR, sv_[e] * accG);
    }
}

extern "C" void kernel_launch(void* const* d_in, const int* in_sizes, int n_in,
                              void* d_out, int out_size, void* d_ws, size_t ws_size,
                              hipStream_t stream) {
    const float* phi    = (const float*)d_in[0];
    const float* w_real = (const float*)d_in[1];
    float* out = (float*)d_out;

    const int n = in_sizes[1] / 4;               // N = 2^20
    const int grid = n / (BLKSZ * ELEMS);        // 1024 blocks, exact
    qsp_fused<<<grid, BLKSZ, 0, stream>>>(phi, w_real, out, n);
}

// Round 7
// 12.371 us; speedup vs baseline: 2.2751x; 1.0231x over previous
//
#include <hip/hip_runtime.h>

// Fused QSP: Re(u00)(a) = a*R(x) + s*Gh(x), x = 2a^2-1, s = sqrt(1-a^2),
// R/Gh deg-31 Chebyshev polys depending only on phi.
// 1024-thread blocks, grid = 256 (exactly 1 block/CU): wave0 builds the
// coeff table (64-node direct iteration + 32-pt DCT-II) once per CU while
// the other 15 waves precompute x,s per element. Then all threads pull the
// 64 coeffs into registers and do shared-T_k dot products, 4 elems/thread.

static constexpr float kInvSqrt2 = 0.70710678118654752440f;
static constexpr float kPiF = 3.14159265358979323846f;

#define QSTEP(c, sp, a, s, m0r, m0i, m1r, m1i)      \
    do {                                            \
        float t0r = fmaf(a, m0r, -(s) * m1i);       \
        float t0i = fmaf(a, m0i,  (s) * m1r);       \
        float t1r = fmaf(a, m1r, -(s) * m0i);       \
        float t1i = fmaf(a, m1i,  (s) * m0r);       \
        m0r = fmaf(c, t0r,  (sp) * t0i);            \
        m0i = fmaf(c, t0i, -(sp) * t0r);            \
        m1r = fmaf(c, t1r, -(sp) * t1i);            \
        m1i = fmaf(c, t1i,  (sp) * t1r);            \
    } while (0)

#define ELEMS 4
#define BLKSZ 1024

__global__ __launch_bounds__(1024, 4) void qsp_fused(
    const float* __restrict__ phi,
    const float* __restrict__ w_real,   // [N*4] floats; a = w_real[4*i]
    float* __restrict__ out,
    int n)
{
    __shared__ float tc[64], ts[64];
    __shared__ float ubuf[64];
    __shared__ float rbuf[32], gbuf[32];
    __shared__ float4 ctab4[16];        // (r_2i, g_2i, r_2i+1, g_2i+1)

    const int t = (int)threadIdx.x;
    const int base = (int)blockIdx.x * (BLKSZ * ELEMS) + t;

    // Issue input loads immediately.
    float av[ELEMS];
#pragma unroll
    for (int e = 0; e < ELEMS; ++e)
        av[e] = w_real[(size_t)(base + e * BLKSZ) * 4];

    // Wave0: phase table.
    if (t < 64) {
        float sv, cv;
        sincosf(0.5f * phi[t], &sv, &cv);
        tc[t] = cv; ts[t] = sv;
    }

    // All waves: coeff-independent per-element prep (hides under coeff wall).
    float xv[ELEMS], sv_[ELEMS], x2v[ELEMS];
#pragma unroll
    for (int e = 0; e < ELEMS; ++e) {
        const float a  = av[e];
        const float aa = a * a;
        xv[e]  = fmaf(2.0f, aa, -1.0f);
        sv_[e] = sqrtf(fmaxf(1.0f - aa, 0.0f));
        x2v[e] = xv[e] + xv[e];
    }
    __syncthreads();

    // Wave0: direct 63-step iteration at 64 Chebyshev nodes.
    if (t < 64) {
        const int j = t & 31;
        float sn, cn;
        sincosf(kPiF * ((float)j + 0.5f) / 64.0f, &sn, &cn);
        const float a = (t < 32) ? cn : -cn;
        const float s = sn;
        const float c0 = tc[0], s0 = ts[0];
        float m0r = kInvSqrt2 * c0, m0i = -kInvSqrt2 * s0;
        float m1r = kInvSqrt2 * c0, m1i =  kInvSqrt2 * s0;
#pragma unroll
        for (int k = 1; k < 64; ++k)
            QSTEP(tc[k], ts[k], a, s, m0r, m0i, m1r, m1i);
        ubuf[t] = (m0r + m1r) * kInvSqrt2;
    }
    __syncthreads();

    // Wave0: even/odd split -> R(x_j), Gh(x_j) samples.
    if (t < 32) {
        float sn, cn;
        sincosf(kPiF * ((float)t + 0.5f) / 64.0f, &sn, &cn);
        const float up = ubuf[t], um = ubuf[t + 32];
        rbuf[t] = (up - um) * (0.5f / cn);
        gbuf[t] = (up + um) * (0.5f / sn);
    }
    __syncthreads();

    // Wave0: 32-point DCT-II -> Chebyshev coeffs (lanes<32 r, lanes>=32 g).
    if (t < 64) {
        const int j = t & 31;
        const float* buf = (t < 32) ? rbuf : gbuf;
        const float stepang = kPiF * (float)j / 32.0f;
        float C, S;  sincosf(stepang, &S, &C);
        float cv, sv; sincosf(0.5f * stepang, &sv, &cv);
        float acc = 0.0f;
#pragma unroll
        for (int m = 0; m < 32; ++m) {
            acc = fmaf(buf[m], cv, acc);
            const float cnx = cv * C - sv * S;
            sv = fmaf(cv, S, sv * C);
            cv = cnx;
        }
        acc *= (j == 0) ? (1.0f / 32.0f) : (2.0f / 32.0f);
        ((float*)ctab4)[(t < 32) ? (2 * j) : (2 * j + 1)] = acc;
    }
    __syncthreads();

    // All threads: coeffs -> registers (broadcast b128), shared-T_k eval.
    float4 cf[16];
#pragma unroll
    for (int i = 0; i < 16; ++i) cf[i] = ctab4[i];

#pragma unroll
    for (int e = 0; e < ELEMS; ++e) {
        const float x  = xv[e];
        const float x2 = x2v[e];
        float accR = fmaf(x, cf[0].z, cf[0].x);
        float accG = fmaf(x, cf[0].w, cf[0].y);
        float tm2 = 1.0f, tm1 = x;
#pragma unroll
        for (int k = 2; k < 32; ++k) {
            const float tk = fmaf(x2, tm1, -tm2);
            const float rk = (k & 1) ? cf[k >> 1].z : cf[k >> 1].x;
            const float gk = (k & 1) ? cf[k >> 1].w : cf[k >> 1].y;
            accR = fmaf(tk, rk, accR);
            accG = fmaf(tk, gk, accG);
            tm2 = tm1; tm1 = tk;
        }
        out[base + e * BLKSZ] = fmaf(av[e], accR, sv_[e] * accG);
    }
}

extern "C" void kernel_launch(void* const* d_in, const int* in_sizes, int n_in,
                              void* d_out, int out_size, void* d_ws, size_t ws_size,
                              hipStream_t stream) {
    const float* phi    = (const float*)d_in[0];
    const float* w_real = (const float*)d_in[1];
    float* out = (float*)d_out;

    const int n = in_sizes[1] / 4;               // N = 2^20
    const int grid = n / (BLKSZ * ELEMS);        // 256 blocks, exact
    qsp_fused<<<grid, BLKSZ, 0, stream>>>(phi, w_real, out, n);
}